// Round 5
// baseline (138.602 us; speedup 1.0000x reference)
//
#include <hip/hip_runtime.h>
#include <hip/hip_cooperative_groups.h>

namespace cg = cooperative_groups;

#define HH 128
#define WW 128
#define HW 16384
#define KK 16
#define NPTS 16384
#define FEAT 64
#define RADIUS2 4.0f
#define EPSV 1e-10f
#define CAP 12          // bucket capacity/cell (Poisson(1): P(>12) ~ 1e-12)

// One cooperative kernel: project+scatter -> grid.sync -> tiled KNN render + feats.
// grid = 256 blocks x 256 threads (4 waves/CU, all co-resident).
__global__ __launch_bounds__(256) void fused_kernel(
        const float* __restrict__ pts,
        const float* __restrict__ intr,
        const float* __restrict__ colors,
        const float* __restrict__ feats,
        int* __restrict__ cell_count,
        float4* __restrict__ buckets,
        float* __restrict__ out_depth, float* __restrict__ out_colors,
        float* __restrict__ out_feats, float* __restrict__ out_mask) {
    __shared__ float4 pts_s[144 * CAP];   // [window-cell][slot], 27.6 KB
    __shared__ int    cnt_s[144];
    __shared__ int    kni_s[64][KK];
    __shared__ float  knw_s[64][KK];

    int tid = threadIdx.x;
    int gid = blockIdx.x * 256 + tid;

    // ---------------- phase 1: project + bucket scatter ----------------
    if (gid < NPTS) {
        float fx = intr[0], cx = intr[2], fy = intr[4], cy = intr[5];
        float x = pts[3 * gid], y = pts[3 * gid + 1], z = pts[3 * gid + 2];
        if (z > 1e-6f) {
            float u = x * fx / z + cx;
            float v = y * fy / z + cy;
            int cu = min(max((int)floorf(u), 0), WW - 1);
            int cv = min(max((int)floorf(v), 0), HH - 1);
            int cell = cv * WW + cu;
            int slot = atomicAdd(&cell_count[cell], 1);
            if (slot < CAP)
                buckets[cell * CAP + slot] = make_float4(u, v, z, __int_as_float(gid));
        }
    }

    cg::this_grid().sync();

    // ---------------- phase 2: tile render ----------------
    int i0 = (blockIdx.x >> 4) * 8;
    int j0 = (blockIdx.x & 15) * 8;

    // stage window cell counts (12x12)
    for (int idx = tid; idx < 144; idx += 256) {
        int r = idx / 12, c = idx - r * 12;
        int ci = i0 - 2 + r, cj = j0 - 2 + c;
        int cnt = 0;
        if (ci >= 0 && ci < HH && cj >= 0 && cj < WW)
            cnt = min(cell_count[ci * WW + cj], CAP);
        cnt_s[idx] = cnt;
    }
    // stage all bucket slots (coalesced contiguous runs per window row)
    for (int idx = tid; idx < 144 * CAP; idx += 256) {
        int cellw = idx / CAP;
        int s = idx - cellw * CAP;
        int r = cellw / 12, c = cellw - r * 12;
        int ci = i0 - 2 + r, cj = j0 - 2 + c;
        if (ci >= 0 && ci < HH && cj >= 0 && cj < WW)
            pts_s[idx] = buckets[(ci * WW + cj) * CAP + s];
    }
    __syncthreads();

    // ---- KNN on waves 0-1: 2 lanes/pixel, 8x8 tile ----
    if (tid < 128) {
        int lp = tid >> 1, lane = tid & 1;
        int li = lp >> 3, lj = lp & 7;
        int i = i0 + li, j = j0 + lj;
        int p = i * WW + j;
        float px = j + 0.5f, py = i + 0.5f;

        float bd[KK];
        int   bt[KK];
#pragma unroll
        for (int k = 0; k < KK; ++k) { bd[k] = 1e30f; bt[k] = -1; }

#pragma unroll
        for (int dr = 0; dr < 5; ++dr) {
            int r = li + dr;
#pragma unroll
            for (int dc = 0; dc < 5; ++dc) {
                int wc = r * 12 + (lj + dc);
                int cnt = cnt_s[wc];
                for (int s = lane; s < cnt; s += 2) {
                    float4 pt = pts_s[wc * CAP + s];
                    float du = pt.x - px, dv = pt.y - py;
                    float d2 = du * du + dv * dv;
                    bool ok = d2 < RADIUS2;
                    float dd = ok ? d2 : 1e30f;
                    int tt = ok ? (wc * CAP + s) : -1;
#pragma unroll
                    for (int k = 0; k < KK; ++k) {
                        bool cc = dd < bd[k];
                        float nb = cc ? dd : bd[k];
                        dd = cc ? bd[k] : dd;
                        int nt = cc ? tt : bt[k];
                        tt = cc ? bt[k] : tt;
                        bd[k] = nb; bt[k] = nt;
                    }
                }
            }
        }

        // cross-lane bitonic min-merge: each lane keeps 8 disjoint winners
        float mb[8]; int mt[8];
#pragma unroll
        for (int k = 0; k < 8; ++k) {
            float obd = __shfl_xor(bd[15 - k], 1);
            int   obt = __shfl_xor(bt[15 - k], 1);
            bool take = obd < bd[k];
            mb[k] = take ? obd : bd[k];
            mt[k] = take ? obt : bt[k];
        }

        float wv[8], dv8[8];
        int idv[8];
        float wsum_l = 0.f;
        int any_l = 0;
#pragma unroll
        for (int k = 0; k < 8; ++k) {
            bool valid = mt[k] >= 0;
            float4 pt = pts_s[valid ? mt[k] : 0];
            float wk = valid ? __expf(-mb[k]) : 0.f;
            wv[k] = wk; wsum_l += wk;
            dv8[k] = valid ? pt.z : 0.f;
            idv[k] = valid ? __float_as_int(pt.w) : 0;  // clamped idx, w=0 guards
            any_l |= valid ? 1 : 0;
        }
        float wsum = wsum_l + __shfl_xor(wsum_l, 1);
        float inv = 1.0f / (wsum + EPSV);

        float cr[8], cg_[8], cbl[8];
#pragma unroll
        for (int k = 0; k < 8; ++k) {
            int n3 = 3 * idv[k];
            cr[k] = colors[n3];
            cg_[k] = colors[n3 + 1];
            cbl[k] = colors[n3 + 2];
        }

        float dsum = 0.f, c0 = 0.f, c1 = 0.f, c2 = 0.f;
#pragma unroll
        for (int k = 0; k < 8; ++k) {
            float wk = wv[k] * inv;
            kni_s[lp][lane * 8 + k] = idv[k];
            knw_s[lp][lane * 8 + k] = wk;
            dsum += dv8[k] * wk;
            c0 += cr[k] * wk;
            c1 += cg_[k] * wk;
            c2 += cbl[k] * wk;
        }

        dsum += __shfl_xor(dsum, 1);
        c0 += __shfl_xor(c0, 1);
        c1 += __shfl_xor(c1, 1);
        c2 += __shfl_xor(c2, 1);
        any_l |= __shfl_xor(any_l, 1);

        if (lane == 0) {
            out_depth[p] = dsum;
            out_colors[3 * p]     = c0;
            out_colors[3 * p + 1] = c1;
            out_colors[3 * p + 2] = c2;
            out_mask[p] = any_l ? 1.0f : 0.0f;
        }
    }
    __syncthreads();

    // ---- feats on all 4 waves: f-lane x 4 pixel-slices ----
    int f = tid & 63;
    int sl = tid >> 6;   // 0..3
    for (int q = sl; q < 64; q += 4) {
        float acc = 0.f;
#pragma unroll
        for (int k = 0; k < KK; ++k) {
            int n = kni_s[q][k];
            float wk = knw_s[q][k];
            acc = fmaf(wk, feats[n * FEAT + f], acc);
        }
        int p = (i0 + (q >> 3)) * WW + j0 + (q & 7);
        out_feats[p * FEAT + f] = acc;
    }
}

extern "C" void kernel_launch(void* const* d_in, const int* in_sizes, int n_in,
                              void* d_out, int out_size, void* d_ws, size_t ws_size,
                              hipStream_t stream) {
    const float* pts    = (const float*)d_in[0];
    const float* colors = (const float*)d_in[1];
    const float* feats  = (const float*)d_in[2];
    const float* intr   = (const float*)d_in[3];

    float* out = (float*)d_out;
    float* out_depth  = out;                  // HW
    float* out_colors = out + HW;             // HW*3
    float* out_feats  = out + HW * 4;         // HW*64
    float* out_mask   = out + HW * 68;        // HW

    char* ws = (char*)d_ws;
    int* cell_count = (int*)ws;                            // 64 KB
    float4* buckets = (float4*)(ws + HW * sizeof(int));    // HW*CAP*16B = 3 MB

    hipMemsetAsync(cell_count, 0, HW * sizeof(int), stream);

    void* args[] = {
        (void*)&pts, (void*)&intr, (void*)&colors, (void*)&feats,
        (void*)&cell_count, (void*)&buckets,
        (void*)&out_depth, (void*)&out_colors, (void*)&out_feats, (void*)&out_mask
    };
    hipLaunchCooperativeKernel((const void*)fused_kernel, dim3(256), dim3(256),
                               args, 0, stream);
}

// Round 6
// 93.234 us; speedup vs baseline: 1.4866x; 1.4866x over previous
//
#include <hip/hip_runtime.h>

#define HH 128
#define WW 128
#define HW 16384
#define KK 16
#define NPTS 16384
#define FEAT 64
#define RADIUS2 4.0f
#define EPSV 1e-10f
#define PCAP 48   // per-pixel candidate capacity; Poisson(12.6) P(>48) ~ 1e-15

// ---------------- kernel 1: project points, append to per-pixel candidate lists ----------------
// Each point's projection (u,v) can be within dist<2 of at most 4x4 pixel centers.
__global__ void project_expand(const float* __restrict__ pts,
                               const float* __restrict__ intr,
                               int* __restrict__ pix_cnt,
                               float2* __restrict__ pairs) {
    int n = blockIdx.x * blockDim.x + threadIdx.x;
    if (n >= NPTS) return;
    float fx = intr[0], cx = intr[2], fy = intr[4], cy = intr[5];
    float x = pts[3 * n], y = pts[3 * n + 1], z = pts[3 * n + 2];
    if (!(z > 1e-6f)) return;           // invalid -> pix=FAR -> never within radius
    float u = x * fx / z + cx;
    float v = y * fy / z + cy;
    int j0 = (int)floorf(u - 2.5f) + 1; // j with |j+0.5-u| < 2  ->  j in (u-2.5, u+1.5)
    int i0 = (int)floorf(v - 2.5f) + 1;
    float idf = __int_as_float(n);
#pragma unroll
    for (int di = 0; di < 4; ++di) {
        int i = i0 + di;
        float dv = (float)i + 0.5f - v;
        bool iok = (i >= 0) & (i < HH);
#pragma unroll
        for (int dj = 0; dj < 4; ++dj) {
            int j = j0 + dj;
            float du = (float)j + 0.5f - u;
            float d2 = du * du + dv * dv;
            if (iok && j >= 0 && j < WW && d2 < RADIUS2) {
                int p = i * WW + j;
                int slot = atomicAdd(&pix_cnt[p], 1);
                if (slot < PCAP)
                    pairs[p * PCAP + slot] = make_float2(d2, idf);
            }
        }
    }
}

// ---------------- kernel 2: per-pixel exact top-16 + depth/color/mask ----------------
// 512 blocks x 64 threads; 32 px/block (8 wide x 4 tall), 2 lanes/pixel.
__global__ __launch_bounds__(64) void render_kernel(
        const float2* __restrict__ pairs,
        const int* __restrict__ pix_cnt,
        const float* __restrict__ pts,
        const float* __restrict__ colors,
        float* __restrict__ out_depth, float* __restrict__ out_colors,
        float* __restrict__ out_mask,
        int* __restrict__ knn_idx, float* __restrict__ knn_w) {
    int tid = threadIdx.x;
    int tile = blockIdx.x;
    int j0 = (tile & 15) * 8;
    int i0 = (tile >> 4) * 4;
    int lp = tid >> 1, lane = tid & 1;
    int li = lp >> 3, lj = lp & 7;
    int p = (i0 + li) * WW + (j0 + lj);

    int cnt = min(pix_cnt[p], PCAP);
    const float2* __restrict__ lst = pairs + p * PCAP;

    float bd[KK];
    int   bt[KK];
#pragma unroll
    for (int k = 0; k < KK; ++k) { bd[k] = 1e30f; bt[k] = -1; }

    // lane takes s = lane, lane+2, ... ; batches of 8 independent loads
    for (int base = lane; base < cnt; base += 16) {
        float2 c[8];
        bool   vb[8];
#pragma unroll
        for (int q = 0; q < 8; ++q) {
            int s = base + 2 * q;
            vb[q] = s < cnt;
            c[q] = lst[min(s, cnt - 1)];
        }
#pragma unroll
        for (int q = 0; q < 8; ++q) {
            float dd = vb[q] ? c[q].x : 1e30f;
            int   tt = vb[q] ? __float_as_int(c[q].y) : -1;
#pragma unroll
            for (int k = 0; k < KK; ++k) {
                bool cc = dd < bd[k];
                float nb = cc ? dd : bd[k];
                dd = cc ? bd[k] : dd;
                int nt = cc ? tt : bt[k];
                tt = cc ? bt[k] : tt;
                bd[k] = nb; bt[k] = nt;
            }
        }
    }

    // cross-lane bitonic min-merge: each lane keeps 8 disjoint winners of the pair's top-16
    float mb[8]; int mt[8];
#pragma unroll
    for (int k = 0; k < 8; ++k) {
        float obd = __shfl_xor(bd[15 - k], 1);
        int   obt = __shfl_xor(bt[15 - k], 1);
        bool take = obd < bd[k];
        mb[k] = take ? obd : bd[k];
        mt[k] = take ? obt : bt[k];
    }

    // weights
    float wv[8];
    float wsum_l = 0.f;
#pragma unroll
    for (int k = 0; k < 8; ++k) {
        bool valid = mt[k] >= 0;
        float wk = valid ? __expf(-mb[k]) : 0.f;   // SIGMA=1
        wv[k] = wk; wsum_l += wk;
    }
    float wsum = wsum_l + __shfl_xor(wsum_l, 1);
    float inv = 1.0f / (wsum + EPSV);

    // batched epilogue gathers: depth (pts z) and colors
    int nn[8];
#pragma unroll
    for (int k = 0; k < 8; ++k) nn[k] = mt[k] >= 0 ? mt[k] : 0;
    float zv[8], cr[8], cg[8], cb[8];
#pragma unroll
    for (int k = 0; k < 8; ++k) {
        zv[k] = pts[3 * nn[k] + 2];
        cr[k] = colors[3 * nn[k]];
        cg[k] = colors[3 * nn[k] + 1];
        cb[k] = colors[3 * nn[k] + 2];
    }

    float dsum = 0.f, c0 = 0.f, c1 = 0.f, c2 = 0.f;
    int   io[8]; float wo[8];
#pragma unroll
    for (int k = 0; k < 8; ++k) {
        float wk = wv[k] * inv;   // exactly 0 for invalid slots
        io[k] = nn[k];            // clamped id; w=0 guards contribution
        wo[k] = wk;
        dsum += zv[k] * wk;
        c0 += cr[k] * wk;
        c1 += cg[k] * wk;
        c2 += cb[k] * wk;
    }

    // handoff: lane0 -> slots 0..7, lane1 -> 8..15 (outputs are order-invariant)
    int4*   ki4 = (int4*)(knn_idx + p * KK + lane * 8);
    float4* kw4 = (float4*)(knn_w + p * KK + lane * 8);
    ki4[0] = make_int4(io[0], io[1], io[2], io[3]);
    ki4[1] = make_int4(io[4], io[5], io[6], io[7]);
    kw4[0] = make_float4(wo[0], wo[1], wo[2], wo[3]);
    kw4[1] = make_float4(wo[4], wo[5], wo[6], wo[7]);

    dsum += __shfl_xor(dsum, 1);
    c0 += __shfl_xor(c0, 1);
    c1 += __shfl_xor(c1, 1);
    c2 += __shfl_xor(c2, 1);

    if (lane == 0) {
        out_depth[p] = dsum;
        out_colors[3 * p]     = c0;
        out_colors[3 * p + 1] = c1;
        out_colors[3 * p + 2] = c2;
        out_mask[p] = (wsum > 0.f) ? 1.0f : 0.0f;
    }
}

// ---------------- kernel 3: feats accumulation, wave-per-pixel, branchless ----------------
__global__ void feats_kernel(const float* __restrict__ feats,
                             const int* __restrict__ knn_idx,
                             const float* __restrict__ knn_w,
                             float* __restrict__ out_feats) {
    int p = blockIdx.x * blockDim.y + threadIdx.y;
    int f = threadIdx.x;  // 0..63
    int nn[KK]; float wk[KK];
#pragma unroll
    for (int k = 0; k < KK; ++k) {
        nn[k] = knn_idx[p * KK + k];
        wk[k] = knn_w[p * KK + k];
    }
    float fv[KK];
#pragma unroll
    for (int k = 0; k < KK; ++k) fv[k] = feats[nn[k] * FEAT + f];
    float acc = 0.f;
#pragma unroll
    for (int k = 0; k < KK; ++k) acc = fmaf(wk[k], fv[k], acc);
    out_feats[p * FEAT + f] = acc;
}

extern "C" void kernel_launch(void* const* d_in, const int* in_sizes, int n_in,
                              void* d_out, int out_size, void* d_ws, size_t ws_size,
                              hipStream_t stream) {
    const float* pts    = (const float*)d_in[0];
    const float* colors = (const float*)d_in[1];
    const float* feats  = (const float*)d_in[2];
    const float* intr   = (const float*)d_in[3];

    float* out = (float*)d_out;
    float* out_depth  = out;                  // HW
    float* out_colors = out + HW;             // HW*3
    float* out_feats  = out + HW * 4;         // HW*64
    float* out_mask   = out + HW * 68;        // HW

    char* ws = (char*)d_ws;
    int* pix_cnt   = (int*)ws;                                   // 64 KB
    float2* pairs  = (float2*)(ws + HW * sizeof(int));           // HW*PCAP*8B = 6 MB
    int* knn_idx   = (int*)(ws + HW * sizeof(int) + (size_t)HW * PCAP * 8);
    float* knn_w   = (float*)((char*)knn_idx + (size_t)HW * KK * 4);

    hipMemsetAsync(pix_cnt, 0, HW * sizeof(int), stream);
    project_expand<<<NPTS / 256, 256, 0, stream>>>(pts, intr, pix_cnt, pairs);
    render_kernel<<<512, 64, 0, stream>>>(pairs, pix_cnt, pts, colors,
                                          out_depth, out_colors, out_mask, knn_idx, knn_w);
    dim3 fb(FEAT, 4);
    feats_kernel<<<HW / 4, fb, 0, stream>>>(feats, knn_idx, knn_w, out_feats);
}